// Round 1
// baseline (1932.200 us; speedup 1.0000x reference)
//
#include <hip/hip_runtime.h>
#include <math.h>

// Problem constants
#define DM 512          // d_model
#define LSEQ 2048
#define BATCH 4
#define NH 8
#define EH 64           // head dim
#define DFF 2048
#define MTOK (BATCH*LSEQ)        // 8192 tokens
#define TM_ELTS (MTOK*DM)        // 4,194,304 floats = 16 MB per token-matrix

// ---------------------------------------------------------------------------
// Tiled fp32 GEMM: C[M,N] = A[M,K] @ B[K,N] + bias, optional exact-erf GELU.
// 64x64 tile, 256 threads, 4x4 per thread, BK=16. LDS stride 68 (conflict pad,
// keeps 16B alignment for float4 stores).
// ---------------------------------------------------------------------------
__global__ __launch_bounds__(256) void gemm_bias_kernel(
    const float* __restrict__ A, const float* __restrict__ B,
    const float* __restrict__ bias, float* __restrict__ C,
    int M, int N, int K, int do_gelu)
{
    __shared__ float As[16][68];   // transposed A tile: As[k][m]
    __shared__ float Bs[16][68];   // Bs[k][n]

    const int tid = threadIdx.x;
    const int tx = tid & 15;       // n group
    const int ty = tid >> 4;       // m group
    const int m0 = blockIdx.y * 64;
    const int n0 = blockIdx.x * 64;

    // A-tile load: 64 rows x 16 cols, one float4 per thread
    const int arow = tid >> 2;          // 0..63
    const int acol = (tid & 3) << 2;    // 0,4,8,12
    // B-tile load: 16 rows x 64 cols, one float4 per thread
    const int brow = tid >> 4;          // 0..15
    const int bcol = (tid & 15) << 2;   // 0..60

    const float* Aptr = A + (m0 + arow) * (long)K + acol;
    const float* Bptr = B + brow * (long)N + n0 + bcol;

    float c[4][4] = {};

    for (int k0 = 0; k0 < K; k0 += 16) {
        float4 a4 = *(const float4*)(Aptr + k0);
        float4 b4 = *(const float4*)(Bptr + (long)k0 * N);
        As[acol + 0][arow] = a4.x;
        As[acol + 1][arow] = a4.y;
        As[acol + 2][arow] = a4.z;
        As[acol + 3][arow] = a4.w;
        *(float4*)&Bs[brow][bcol] = b4;
        __syncthreads();
        #pragma unroll
        for (int k = 0; k < 16; ++k) {
            float a[4], b[4];
            #pragma unroll
            for (int i = 0; i < 4; ++i) a[i] = As[k][ty * 4 + i];
            #pragma unroll
            for (int j = 0; j < 4; ++j) b[j] = Bs[k][tx * 4 + j];
            #pragma unroll
            for (int i = 0; i < 4; ++i)
                #pragma unroll
                for (int j = 0; j < 4; ++j)
                    c[i][j] += a[i] * b[j];
        }
        __syncthreads();
    }

    #pragma unroll
    for (int i = 0; i < 4; ++i) {
        const int row = m0 + ty * 4 + i;
        float* outp = C + (long)row * N + n0 + tx * 4;
        const float* bp = bias + n0 + tx * 4;
        float4 v;
        v.x = c[i][0] + bp[0];
        v.y = c[i][1] + bp[1];
        v.z = c[i][2] + bp[2];
        v.w = c[i][3] + bp[3];
        if (do_gelu) {
            v.x = 0.5f * v.x * (1.0f + erff(v.x * 0.70710678118654752f));
            v.y = 0.5f * v.y * (1.0f + erff(v.y * 0.70710678118654752f));
            v.z = 0.5f * v.z * (1.0f + erff(v.z * 0.70710678118654752f));
            v.w = 0.5f * v.w * (1.0f + erff(v.w * 0.70710678118654752f));
        }
        *(float4*)outp = v;
    }
}

// ---------------------------------------------------------------------------
// Flash-style attention, fp32. One block = (b, h, 64-query tile).
// Q/K/V laid out [B, L, H*E] (natural GEMM output). Online softmax.
// K-tile LDS buffer is reused to hold P after scores are consumed.
// Thread (r = tid/4, cq = tid%4) owns row r, interleaved cols/dims 4*jj+cq
// (interleaving keeps the 4-address groups in distinct LDS banks).
// ---------------------------------------------------------------------------
__global__ __launch_bounds__(256) void flash_attn_kernel(
    const float* __restrict__ Q, const float* __restrict__ K,
    const float* __restrict__ V, float* __restrict__ O)
{
    __shared__ float Qs[64][68];
    __shared__ float KPs[64][68];  // K tile, then P tile
    __shared__ float Vs[64][68];

    const int idx = blockIdx.x;        // 1024 blocks
    const int qt = idx & 31;           // L/64 = 32 query tiles
    const int h  = (idx >> 5) & 7;
    const int b  = idx >> 8;
    const int tid = threadIdx.x;
    const int r  = tid >> 2;           // 0..63 query row in tile
    const int cq = tid & 3;

    const long base = (long)b * LSEQ * DM + h * EH;  // (b, l=0, h, e=0)
    const int q0 = qt * 64;

    // Load Q tile (64x64), 4 float4 per thread, coalesced
    {
        const int e0 = tid * 4;
        #pragma unroll
        for (int i = 0; i < 4; ++i) {
            const int e = e0 + i * 1024;
            const int row = e >> 6, col = e & 63;
            *(float4*)&Qs[row][col] =
                *(const float4*)(Q + base + (long)(q0 + row) * DM + col);
        }
    }

    float m_i = -1e30f, l_i = 0.0f;
    float acc[16];
    #pragma unroll
    for (int i = 0; i < 16; ++i) acc[i] = 0.0f;

    for (int kt = 0; kt < LSEQ / 64; ++kt) {
        const int k0 = kt * 64;
        __syncthreads();  // prior iter done reading KPs(P)/Vs; also covers Qs on iter 0
        {
            const int e0 = tid * 4;
            #pragma unroll
            for (int i = 0; i < 4; ++i) {
                const int e = e0 + i * 1024;
                const int row = e >> 6, col = e & 63;
                *(float4*)&KPs[row][col] =
                    *(const float4*)(K + base + (long)(k0 + row) * DM + col);
                *(float4*)&Vs[row][col] =
                    *(const float4*)(V + base + (long)(k0 + row) * DM + col);
            }
        }
        __syncthreads();

        // scores for cols c = 4*jj + cq
        float s[16];
        #pragma unroll
        for (int jj = 0; jj < 16; ++jj) s[jj] = 0.0f;
        for (int k = 0; k < 64; ++k) {
            const float qv = Qs[r][k];
            #pragma unroll
            for (int jj = 0; jj < 16; ++jj)
                s[jj] += qv * KPs[4 * jj + cq][k];
        }
        float mloc = -1e30f;
        #pragma unroll
        for (int jj = 0; jj < 16; ++jj) {
            s[jj] *= 0.125f;  // 1/sqrt(64)
            mloc = fmaxf(mloc, s[jj]);
        }
        // quad (same row) reductions
        mloc = fmaxf(mloc, __shfl_xor(mloc, 1));
        mloc = fmaxf(mloc, __shfl_xor(mloc, 2));
        const float m_new = fmaxf(m_i, mloc);
        const float alpha = __expf(m_i - m_new);
        float psum = 0.0f;
        #pragma unroll
        for (int jj = 0; jj < 16; ++jj) {
            s[jj] = __expf(s[jj] - m_new);
            psum += s[jj];
        }
        psum += __shfl_xor(psum, 1);
        psum += __shfl_xor(psum, 2);
        l_i = l_i * alpha + psum;
        m_i = m_new;
        #pragma unroll
        for (int i = 0; i < 16; ++i) acc[i] *= alpha;

        __syncthreads();  // all threads done reading KPs as K
        #pragma unroll
        for (int jj = 0; jj < 16; ++jj)
            KPs[r][4 * jj + cq] = s[jj];
        __syncthreads();

        // acc[dd] += sum_j P[r][j] * V[j][4*dd+cq]
        for (int j = 0; j < 64; ++j) {
            const float p = KPs[r][j];
            #pragma unroll
            for (int dd = 0; dd < 16; ++dd)
                acc[dd] += p * Vs[j][4 * dd + cq];
        }
    }

    const float inv = 1.0f / l_i;
    float* outp = O + base + (long)(q0 + r) * DM;
    #pragma unroll
    for (int dd = 0; dd < 16; ++dd)
        outp[4 * dd + cq] = acc[dd] * inv;
}

// ---------------------------------------------------------------------------
// out[row] = LayerNorm(X[row] + R[row]) * g + beta, row = 512 elems,
// one 256-thread block per row.
// ---------------------------------------------------------------------------
__global__ __launch_bounds__(256) void add_ln_kernel(
    const float* __restrict__ X, const float* __restrict__ R,
    const float* __restrict__ g, const float* __restrict__ beta,
    float* __restrict__ out)
{
    const int row = blockIdx.x;
    const int tid = threadIdx.x;
    const float* xp = X + (long)row * DM;
    const float* rp = R + (long)row * DM;

    const float v0 = xp[tid] + rp[tid];
    const float v1 = xp[tid + 256] + rp[tid + 256];
    float s = v0 + v1;
    float sq = v0 * v0 + v1 * v1;
    #pragma unroll
    for (int o = 32; o > 0; o >>= 1) {
        s += __shfl_down(s, o);
        sq += __shfl_down(sq, o);
    }
    __shared__ float ss[4], ssq[4];
    const int wid = tid >> 6, lane = tid & 63;
    if (lane == 0) { ss[wid] = s; ssq[wid] = sq; }
    __syncthreads();
    const float S  = ss[0] + ss[1] + ss[2] + ss[3];
    const float SQ = ssq[0] + ssq[1] + ssq[2] + ssq[3];
    const float mean = S * (1.0f / DM);
    const float var = SQ * (1.0f / DM) - mean * mean;
    const float rstd = rsqrtf(var + 1e-5f);
    float* op = out + (long)row * DM;
    op[tid]       = (v0 - mean) * rstd * g[tid] + beta[tid];
    op[tid + 256] = (v1 - mean) * rstd * g[tid + 256] + beta[tid + 256];
}

// ---------------------------------------------------------------------------
extern "C" void kernel_launch(void* const* d_in, const int* in_sizes, int n_in,
                              void* d_out, int out_size, void* d_ws, size_t ws_size,
                              hipStream_t stream)
{
    const float* x   = (const float*)d_in[0];
    const float* Wq  = (const float*)d_in[1];
    const float* bq  = (const float*)d_in[2];
    const float* Wk  = (const float*)d_in[3];
    const float* bk  = (const float*)d_in[4];
    const float* Wv  = (const float*)d_in[5];
    const float* bv  = (const float*)d_in[6];
    const float* Wo  = (const float*)d_in[7];
    const float* bo  = (const float*)d_in[8];
    const float* W1  = (const float*)d_in[9];
    const float* b1  = (const float*)d_in[10];
    const float* W2  = (const float*)d_in[11];
    const float* b2  = (const float*)d_in[12];
    const float* g1  = (const float*)d_in[13];
    const float* be1 = (const float*)d_in[14];
    const float* g2  = (const float*)d_in[15];
    const float* be2 = (const float*)d_in[16];
    float* out = (float*)d_out;

    float* ws = (float*)d_ws;
    float* qb   = ws;                // 16 MB each region
    float* kb   = ws + (long)TM_ELTS;
    float* vb   = ws + 2L * TM_ELTS;
    float* sb   = ws + 3L * TM_ELTS; // attn out / ffn out scratch
    // reuse after attention:
    float* attn_out = qb;
    float* x1       = kb;
    float* hb       = vb;            // FFN hidden chunk (2048x2048 = 16 MB)

    const dim3 blk(256);
    const dim3 gProj(DM / 64, MTOK / 64);   // (8, 128)

    // QKV projections
    gemm_bias_kernel<<<gProj, blk, 0, stream>>>(x, Wq, bq, qb, MTOK, DM, DM, 0);
    gemm_bias_kernel<<<gProj, blk, 0, stream>>>(x, Wk, bk, kb, MTOK, DM, DM, 0);
    gemm_bias_kernel<<<gProj, blk, 0, stream>>>(x, Wv, bv, vb, MTOK, DM, DM, 0);

    // attention -> sb
    flash_attn_kernel<<<dim3(BATCH * NH * (LSEQ / 64)), blk, 0, stream>>>(qb, kb, vb, sb);

    // output projection -> attn_out (q region, q is dead)
    gemm_bias_kernel<<<gProj, blk, 0, stream>>>(sb, Wo, bo, attn_out, MTOK, DM, DM, 0);

    // x1 = LN(x + attn_out)
    add_ln_kernel<<<dim3(MTOK), blk, 0, stream>>>(x, attn_out, g1, be1, x1);

    // FFN in 4 row-chunks of 2048 (h chunk fits in one 16 MB region)
    const int CH = 2048;
    const dim3 gF1(DFF / 64, CH / 64);  // (32, 32)
    const dim3 gF2(DM / 64, CH / 64);   // (8, 32)
    for (int c = 0; c < 4; ++c) {
        const float* x1c = x1 + (long)c * CH * DM;
        float* fc = sb + (long)c * CH * DM;
        gemm_bias_kernel<<<gF1, blk, 0, stream>>>(x1c, W1, b1, hb, CH, DFF, DM, 1);
        gemm_bias_kernel<<<gF2, blk, 0, stream>>>(hb, W2, b2, fc, CH, DM, DFF, 0);
    }

    // out = LN(x1 + ffn_out)
    add_ln_kernel<<<dim3(MTOK), blk, 0, stream>>>(x1, sb, g2, be2, out);
}

// Round 2
// 468.434 us; speedup vs baseline: 4.1248x; 4.1248x over previous
//
#include <hip/hip_runtime.h>
#include <math.h>

// Problem constants
#define DM 512
#define LSEQ 2048
#define BATCH 4
#define NH 8
#define EH 64
#define DFF 2048
#define MTOK (BATCH*LSEQ)   // 8192
#define QKVW 1536           // fused qkv width

using short8  = __attribute__((ext_vector_type(8))) short;
using floatx4 = __attribute__((ext_vector_type(4))) float;

// fp32 -> bf16 round-to-nearest-even
__device__ __forceinline__ short f2b(float f) {
    unsigned u = __float_as_uint(f);
    unsigned r = u + 0x7FFFu + ((u >> 16) & 1u);
    return (short)(r >> 16);
}

// ---------------------------------------------------------------------------
// Transpose + convert: out[c][r] = (bf16) in[r][c].  in is [R][C] fp32.
// Grid: (C/64, R/64), 256 threads.
// ---------------------------------------------------------------------------
__global__ __launch_bounds__(256) void transpose_cvt(
    const float* __restrict__ in, short* __restrict__ out, int R, int C)
{
    __shared__ float t[64][65];
    const int tid = threadIdx.x;
    const int r0 = blockIdx.y * 64, c0 = blockIdx.x * 64;
    const int r = tid >> 2, cs = (tid & 3) * 16;
    const float* ip = in + (long)(r0 + r) * C + c0 + cs;
    #pragma unroll
    for (int i = 0; i < 4; ++i) {
        float4 v = *(const float4*)(ip + i * 4);
        t[r][cs + i*4 + 0] = v.x;
        t[r][cs + i*4 + 1] = v.y;
        t[r][cs + i*4 + 2] = v.z;
        t[r][cs + i*4 + 3] = v.w;
    }
    __syncthreads();
    short tmp[16];
    #pragma unroll
    for (int j = 0; j < 16; ++j) tmp[j] = f2b(t[cs + j][r]);
    short* op = out + (long)(c0 + r) * R + r0 + cs;
    *(float4*)op       = *(float4*)&tmp[0];
    *(float4*)(op + 8) = *(float4*)&tmp[8];
}

// fused qkv bias: bqkv[0:512)=bq, [512:1024)=bk, [1024:1536)=bv
__global__ void fuse_bias_kernel(const float* __restrict__ bq,
                                 const float* __restrict__ bk,
                                 const float* __restrict__ bv,
                                 float* __restrict__ bqkv)
{
    int i = blockIdx.x * 256 + threadIdx.x;
    if (i < QKVW) {
        float v = (i < 512) ? bq[i] : (i < 1024 ? bk[i - 512] : bv[i - 1024]);
        bqkv[i] = v;
    }
}

// ---------------------------------------------------------------------------
// MFMA bf16 GEMM: C[M,N] = A[M,K] @ B[K,N] + bias (B passed as Bt[n][k] bf16).
// 128x128 tile, BK=32, 4 waves in 2x2, each wave 4x4 tiles of 16x16x32.
// A is fp32 (converted during staging) or bf16 per template arg.
// ---------------------------------------------------------------------------
template<int A_F32, int OUT_F32, int DO_GELU>
__global__ __launch_bounds__(256) void mfma_gemm(
    const void* __restrict__ Av, const short* __restrict__ Bt,
    const float* __restrict__ bias, void* __restrict__ Cv,
    int M, int N, int K, int lda, int ldc)
{
    __shared__ short As[128][40];   // [m][k], pad 40 => 2-way free
    __shared__ short Bs[128][40];   // [n][k]

    const int tid  = threadIdx.x;
    const int wave = tid >> 6;
    const int lane = tid & 63;
    const int qd   = lane >> 4;
    const int sl   = lane & 15;
    const int m0 = blockIdx.y * 128;
    const int n0 = blockIdx.x * 128;
    const int wm = (wave & 1) * 64;
    const int wn = (wave >> 1) * 64;

    const int sr = tid >> 1;          // staging row 0..127
    const int sh = (tid & 1) * 16;    // k-half

    floatx4 acc[4][4];
    const floatx4 fz = {0.f, 0.f, 0.f, 0.f};
    #pragma unroll
    for (int i = 0; i < 4; ++i)
        #pragma unroll
        for (int j = 0; j < 4; ++j) acc[i][j] = fz;

    for (int k0 = 0; k0 < K; k0 += 32) {
        if (A_F32) {
            const float* Ap = (const float*)Av + (long)(m0 + sr) * lda + k0 + sh;
            float4 f0 = *(const float4*)(Ap + 0);
            float4 f1 = *(const float4*)(Ap + 4);
            float4 f2 = *(const float4*)(Ap + 8);
            float4 f3 = *(const float4*)(Ap + 12);
            short tmp[16];
            tmp[0]=f2b(f0.x); tmp[1]=f2b(f0.y); tmp[2]=f2b(f0.z); tmp[3]=f2b(f0.w);
            tmp[4]=f2b(f1.x); tmp[5]=f2b(f1.y); tmp[6]=f2b(f1.z); tmp[7]=f2b(f1.w);
            tmp[8]=f2b(f2.x); tmp[9]=f2b(f2.y); tmp[10]=f2b(f2.z); tmp[11]=f2b(f2.w);
            tmp[12]=f2b(f3.x); tmp[13]=f2b(f3.y); tmp[14]=f2b(f3.z); tmp[15]=f2b(f3.w);
            *(float4*)&As[sr][sh]     = *(float4*)&tmp[0];
            *(float4*)&As[sr][sh + 8] = *(float4*)&tmp[8];
        } else {
            const short* Ap = (const short*)Av + (long)(m0 + sr) * lda + k0 + sh;
            *(float4*)&As[sr][sh]     = *(const float4*)Ap;
            *(float4*)&As[sr][sh + 8] = *(const float4*)(Ap + 8);
        }
        {
            const short* Bp = Bt + (long)(n0 + sr) * K + k0 + sh;
            *(float4*)&Bs[sr][sh]     = *(const float4*)Bp;
            *(float4*)&Bs[sr][sh + 8] = *(const float4*)(Bp + 8);
        }
        __syncthreads();

        short8 af[4], bfr[4];
        #pragma unroll
        for (int t = 0; t < 4; ++t) {
            af[t]  = *(const short8*)&As[wm + t*16 + sl][qd*8];
            bfr[t] = *(const short8*)&Bs[wn + t*16 + sl][qd*8];
        }
        #pragma unroll
        for (int i = 0; i < 4; ++i)
            #pragma unroll
            for (int j = 0; j < 4; ++j)
                acc[i][j] = __builtin_amdgcn_mfma_f32_16x16x32_bf16(
                    af[i], bfr[j], acc[i][j], 0, 0, 0);
        __syncthreads();
    }

    // epilogue: D row = qd*4+reg, col = sl within each 16x16 tile
    #pragma unroll
    for (int j = 0; j < 4; ++j) {
        const int col = n0 + wn + j*16 + sl;
        const float bv = bias[col];
        #pragma unroll
        for (int i = 0; i < 4; ++i) {
            #pragma unroll
            for (int r = 0; r < 4; ++r) {
                const int row = m0 + wm + i*16 + qd*4 + r;
                float v = acc[i][j][r] + bv;
                if (DO_GELU) v = 0.5f * v * (1.0f + erff(v * 0.70710678118654752f));
                if (OUT_F32) ((float*)Cv)[(long)row * ldc + col] = v;
                else         ((short*)Cv)[(long)row * ldc + col] = f2b(v);
            }
        }
    }
}

// ---------------------------------------------------------------------------
// Flash attention, bf16 MFMA. One block = (b, h, 64-query tile); 4 waves,
// each wave owns a 16-row query strip. 64 keys per iteration.
// QKV layout [8192][1536] bf16 (q|k|v). O written back into the q-slice
// (each block's q region is read only by itself).
// ---------------------------------------------------------------------------
__global__ __launch_bounds__(256) void mfma_attn(
    const short* __restrict__ QKV, short* __restrict__ O)
{
    __shared__ short Qs[64][72];
    __shared__ short Ks[64][72];
    __shared__ short Vt[64][72];       // V transposed: Vt[e][key]
    __shared__ short Ps[4][16][72];    // per-wave P strip

    const int tid  = threadIdx.x;
    const int wave = tid >> 6;
    const int lane = tid & 63;
    const int qd   = lane >> 4;
    const int sl   = lane & 15;

    const int blk = blockIdx.x;
    const int qt = blk & 31;
    const int h  = (blk >> 5) & 7;
    const int b  = blk >> 8;

    const long base = (long)b * LSEQ * QKVW;
    const int q0 = qt * 64;

    const int lr = tid >> 2;
    const int lc = (tid & 3) * 16;

    {   // Q tile: rows q0..+63, cols h*64..+63
        const short* qp = QKV + base + (long)(q0 + lr) * QKVW + h * EH + lc;
        *(float4*)&Qs[lr][lc]     = *(const float4*)qp;
        *(float4*)&Qs[lr][lc + 8] = *(const float4*)(qp + 8);
    }

    float m_i[4], l_i[4];
    floatx4 oacc[4];
    const floatx4 fz = {0.f, 0.f, 0.f, 0.f};
    #pragma unroll
    for (int r = 0; r < 4; ++r) { m_i[r] = -1e30f; l_i[r] = 0.f; }
    #pragma unroll
    for (int t = 0; t < 4; ++t) oacc[t] = fz;

    const int vkk = tid & 63;
    const int ve0 = (tid >> 6) * 16;

    for (int kt = 0; kt < LSEQ / 64; ++kt) {
        const int k0 = kt * 64;
        __syncthreads();   // prior iter done reading Ks/Vt (covers Qs on iter 0)
        {   // K tile
            const short* kp = QKV + base + (long)(k0 + lr) * QKVW + 512 + h * EH + lc;
            *(float4*)&Ks[lr][lc]     = *(const float4*)kp;
            *(float4*)&Ks[lr][lc + 8] = *(const float4*)(kp + 8);
        }
        {   // V^T tile
            const short* vp = QKV + base + (long)(k0 + vkk) * QKVW + 1024 + h * EH + ve0;
            short tmp[16];
            *(float4*)&tmp[0] = *(const float4*)vp;
            *(float4*)&tmp[8] = *(const float4*)(vp + 8);
            #pragma unroll
            for (int i = 0; i < 16; ++i) Vt[ve0 + i][vkk] = tmp[i];
        }
        __syncthreads();

        // S = Q K^T  (A-frag from Qs, B-frag from Ks; both row=sl, k=qd*8)
        floatx4 s[4];
        #pragma unroll
        for (int t = 0; t < 4; ++t) s[t] = fz;
        #pragma unroll
        for (int ks = 0; ks < 2; ++ks) {
            short8 aq = *(const short8*)&Qs[wave*16 + sl][ks*32 + qd*8];
            #pragma unroll
            for (int t = 0; t < 4; ++t) {
                short8 bk = *(const short8*)&Ks[t*16 + sl][ks*32 + qd*8];
                s[t] = __builtin_amdgcn_mfma_f32_16x16x32_bf16(aq, bk, s[t], 0, 0, 0);
            }
        }

        // online softmax; row = qd*4+r, cols spread over (t, sl)
        float p[4][4];
        #pragma unroll
        for (int r = 0; r < 4; ++r) {
            float mx = -1e30f;
            #pragma unroll
            for (int t = 0; t < 4; ++t) {
                float sv = s[t][r] * 0.125f;   // 1/sqrt(64)
                p[t][r] = sv;
                mx = fmaxf(mx, sv);
            }
            mx = fmaxf(mx, __shfl_xor(mx, 1));
            mx = fmaxf(mx, __shfl_xor(mx, 2));
            mx = fmaxf(mx, __shfl_xor(mx, 4));
            mx = fmaxf(mx, __shfl_xor(mx, 8));
            const float mnew  = fmaxf(m_i[r], mx);
            const float alpha = __expf(m_i[r] - mnew);
            float rs = 0.f;
            #pragma unroll
            for (int t = 0; t < 4; ++t) {
                p[t][r] = __expf(p[t][r] - mnew);
                rs += p[t][r];
            }
            rs += __shfl_xor(rs, 1);
            rs += __shfl_xor(rs, 2);
            rs += __shfl_xor(rs, 4);
            rs += __shfl_xor(rs, 8);
            l_i[r] = l_i[r] * alpha + rs;
            m_i[r] = mnew;
            #pragma unroll
            for (int t = 0; t < 4; ++t) oacc[t][r] *= alpha;
        }

        // P: C-layout -> LDS (bf16) -> A-layout (per-wave buffer, no barrier)
        #pragma unroll
        for (int t = 0; t < 4; ++t)
            #pragma unroll
            for (int r = 0; r < 4; ++r)
                Ps[wave][qd*4 + r][t*16 + sl] = f2b(p[t][r]);

        // O += P V   (B-frag from Vt: row=e, contiguous key)
        #pragma unroll
        for (int ks = 0; ks < 2; ++ks) {
            short8 ap = *(const short8*)&Ps[wave][sl][ks*32 + qd*8];
            #pragma unroll
            for (int t = 0; t < 4; ++t) {
                short8 bv = *(const short8*)&Vt[t*16 + sl][ks*32 + qd*8];
                oacc[t] = __builtin_amdgcn_mfma_f32_16x16x32_bf16(ap, bv, oacc[t], 0, 0, 0);
            }
        }
    }

    float inv[4];
    #pragma unroll
    for (int r = 0; r < 4; ++r) inv[r] = 1.0f / l_i[r];
    #pragma unroll
    for (int t = 0; t < 4; ++t)
        #pragma unroll
        for (int r = 0; r < 4; ++r) {
            const int row = q0 + wave*16 + qd*4 + r;
            const int col = h * EH + t*16 + sl;
            O[base + (long)row * QKVW + col] = f2b(oacc[t][r] * inv[r]);
        }
}

// ---------------------------------------------------------------------------
// out[row] = LayerNorm(X[row] + R[row]) * g + beta  (row = 512 fp32)
// ---------------------------------------------------------------------------
__global__ __launch_bounds__(256) void add_ln_kernel(
    const float* __restrict__ X, const float* __restrict__ R,
    const float* __restrict__ g, const float* __restrict__ beta,
    float* __restrict__ out)
{
    const int row = blockIdx.x;
    const int tid = threadIdx.x;
    const float* xp = X + (long)row * DM;
    const float* rp = R + (long)row * DM;

    const float v0 = xp[tid] + rp[tid];
    const float v1 = xp[tid + 256] + rp[tid + 256];
    float s = v0 + v1;
    float sq = v0 * v0 + v1 * v1;
    #pragma unroll
    for (int o = 32; o > 0; o >>= 1) {
        s  += __shfl_down(s, o);
        sq += __shfl_down(sq, o);
    }
    __shared__ float ss[4], ssq[4];
    const int wid = tid >> 6, lane = tid & 63;
    if (lane == 0) { ss[wid] = s; ssq[wid] = sq; }
    __syncthreads();
    const float S  = ss[0] + ss[1] + ss[2] + ss[3];
    const float SQ = ssq[0] + ssq[1] + ssq[2] + ssq[3];
    const float mean = S * (1.0f / DM);
    const float var  = SQ * (1.0f / DM) - mean * mean;
    const float rstd = rsqrtf(var + 1e-5f);
    float* op = out + (long)row * DM;
    op[tid]       = (v0 - mean) * rstd * g[tid] + beta[tid];
    op[tid + 256] = (v1 - mean) * rstd * g[tid + 256] + beta[tid + 256];
}

// ---------------------------------------------------------------------------
extern "C" void kernel_launch(void* const* d_in, const int* in_sizes, int n_in,
                              void* d_out, int out_size, void* d_ws, size_t ws_size,
                              hipStream_t stream)
{
    const float* x   = (const float*)d_in[0];
    const float* Wq  = (const float*)d_in[1];
    const float* bq  = (const float*)d_in[2];
    const float* Wk  = (const float*)d_in[3];
    const float* bk  = (const float*)d_in[4];
    const float* Wv  = (const float*)d_in[5];
    const float* bv  = (const float*)d_in[6];
    const float* Wo  = (const float*)d_in[7];
    const float* bo  = (const float*)d_in[8];
    const float* W1  = (const float*)d_in[9];
    const float* b1  = (const float*)d_in[10];
    const float* W2  = (const float*)d_in[11];
    const float* b2  = (const float*)d_in[12];
    const float* g1  = (const float*)d_in[13];
    const float* be1 = (const float*)d_in[14];
    const float* g2  = (const float*)d_in[15];
    const float* be2 = (const float*)d_in[16];
    float* out = (float*)d_out;

    // ---- workspace layout (≈62.3 MB total) ----
    short* Wqkvt = (short*)d_ws;                       // [1536][512] bf16
    short* Wot   = Wqkvt + (long)QKVW * DM;            // [512][512]
    short* W1t   = Wot   + (long)DM * DM;              // [2048][512]
    short* W2t   = W1t   + (long)DFF * DM;             // [512][2048]
    float* bqkv  = (float*)(W2t + (long)DM * DFF);     // [1536] fp32
    short* qkv   = (short*)((char*)bqkv + QKVW * sizeof(float)); // [8192][1536] bf16
    float* attn_out = (float*)(qkv + (long)MTOK * QKVW);         // [8192][512] fp32
    float* x1    = attn_out + (long)MTOK * DM;                   // [8192][512] fp32
    short* h     = qkv;          // FFN hidden chunk overlays qkv (dead)
    float* ffn   = attn_out;     // ffn out overlays attn_out (dead)

    const dim3 blk(256);

    // weight conversion (transposed bf16) + fused qkv bias
    fuse_bias_kernel<<<dim3(6), blk, 0, stream>>>(bq, bk, bv, bqkv);
    transpose_cvt<<<dim3(8, 8),  blk, 0, stream>>>(Wq, Wqkvt,                 DM, DM);
    transpose_cvt<<<dim3(8, 8),  blk, 0, stream>>>(Wk, Wqkvt + 512L * DM,     DM, DM);
    transpose_cvt<<<dim3(8, 8),  blk, 0, stream>>>(Wv, Wqkvt + 1024L * DM,    DM, DM);
    transpose_cvt<<<dim3(8, 8),  blk, 0, stream>>>(Wo, Wot, DM, DM);
    transpose_cvt<<<dim3(32, 8), blk, 0, stream>>>(W1, W1t, DM, DFF);
    transpose_cvt<<<dim3(8, 32), blk, 0, stream>>>(W2, W2t, DFF, DM);

    // fused QKV projection: [8192,512] x [512,1536]
    mfma_gemm<1, 0, 0><<<dim3(QKVW / 128, MTOK / 128), blk, 0, stream>>>(
        x, Wqkvt, bqkv, qkv, MTOK, QKVW, DM, DM, QKVW);

    // attention (O -> q-slice of qkv)
    mfma_attn<<<dim3(BATCH * NH * (LSEQ / 64)), blk, 0, stream>>>(qkv, qkv);

    // output projection (A = O bf16, lda=1536) -> fp32
    mfma_gemm<0, 1, 0><<<dim3(DM / 128, MTOK / 128), blk, 0, stream>>>(
        qkv, Wot, bo, attn_out, MTOK, DM, DM, QKVW, DM);

    // x1 = LN(x + attn_out)
    add_ln_kernel<<<dim3(MTOK), blk, 0, stream>>>(x, attn_out, g1, be1, x1);

    // FFN in 2 row-chunks of 4096 (h chunk = 16 MB fits in qkv region)
    for (int c = 0; c < 2; ++c) {
        const float* x1c = x1  + (long)c * 4096 * DM;
        float*       fc  = ffn + (long)c * 4096 * DM;
        mfma_gemm<1, 0, 1><<<dim3(DFF / 128, 4096 / 128), blk, 0, stream>>>(
            x1c, W1t, b1, h, 4096, DFF, DM, DM, DFF);
        mfma_gemm<0, 1, 0><<<dim3(DM / 128, 4096 / 128), blk, 0, stream>>>(
            h, W2t, b2, fc, 4096, DM, DFF, DFF, DM);
    }

    // out = LN(x1 + ffn)
    add_ln_kernel<<<dim3(MTOK), blk, 0, stream>>>(x1, ffn, g2, be2, out);
}

// Round 3
// 331.681 us; speedup vs baseline: 5.8255x; 1.4123x over previous
//
#include <hip/hip_runtime.h>
#include <math.h>

#define DM 512
#define LSEQ 2048
#define BATCH 4
#define NH 8
#define EH 64
#define DFF 2048
#define MTOK (BATCH*LSEQ)   // 8192
#define QKVW 1536
// 0.125 (1/sqrt(64)) * log2(e), folded into Q so softmax uses raw exp2
#define QSCL 0.18033688011112042f

using short8  = __attribute__((ext_vector_type(8))) short;
using floatx4 = __attribute__((ext_vector_type(4))) float;

__device__ __forceinline__ short f2b(float f) {           // RNE fp32->bf16
    unsigned u = __float_as_uint(f);
    return (short)((u + 0x7FFFu + ((u >> 16) & 1u)) >> 16);
}
__device__ __forceinline__ float b2f(short s) {
    return __uint_as_float(((unsigned)(unsigned short)s) << 16);
}
__device__ __forceinline__ void load_lds16(const short* g, short* l) {
    __builtin_amdgcn_global_load_lds(
        (const __attribute__((address_space(1))) void*)g,
        (__attribute__((address_space(3))) void*)l, 16, 0, 0);
}

// ---------------------------------------------------------------------------
// Weight transpose + cvt: out[c][r] = bf16(in[r][c]); in [R][C] fp32.
// ---------------------------------------------------------------------------
__global__ __launch_bounds__(256) void transpose_cvt(
    const float* __restrict__ in, short* __restrict__ out, int R, int C)
{
    __shared__ float t[64][65];
    const int tid = threadIdx.x;
    const int r0 = blockIdx.y * 64, c0 = blockIdx.x * 64;
    const int r = tid >> 2, cs = (tid & 3) * 16;
    const float* ip = in + (long)(r0 + r) * C + c0 + cs;
    #pragma unroll
    for (int i = 0; i < 4; ++i) {
        float4 v = *(const float4*)(ip + i * 4);
        t[r][cs + i*4 + 0] = v.x; t[r][cs + i*4 + 1] = v.y;
        t[r][cs + i*4 + 2] = v.z; t[r][cs + i*4 + 3] = v.w;
    }
    __syncthreads();
    short tmp[16];
    #pragma unroll
    for (int j = 0; j < 16; ++j) tmp[j] = f2b(t[cs + j][r]);
    short* op = out + (long)(c0 + r) * R + r0 + cs;
    *(float4*)op       = *(float4*)&tmp[0];
    *(float4*)(op + 8) = *(float4*)&tmp[8];
}

__global__ void fuse_bias_kernel(const float* __restrict__ bq,
                                 const float* __restrict__ bk,
                                 const float* __restrict__ bv,
                                 float* __restrict__ bqkv)
{
    int i = blockIdx.x * 256 + threadIdx.x;
    if (i < QKVW)
        bqkv[i] = (i < 512) ? bq[i] : (i < 1024 ? bk[i - 512] : bv[i - 1024]);
}

// x fp32 -> bf16, 8 elems/thread
__global__ __launch_bounds__(256) void cvt_f32_bf16(
    const float* __restrict__ in, short* __restrict__ out)
{
    const int i = (blockIdx.x * 256 + threadIdx.x) * 8;
    float4 a = *(const float4*)(in + i);
    float4 b = *(const float4*)(in + i + 4);
    short t[8] = { f2b(a.x), f2b(a.y), f2b(a.z), f2b(a.w),
                   f2b(b.x), f2b(b.y), f2b(b.z), f2b(b.w) };
    *(float4*)(out + i) = *(float4*)t;
}

// ---------------------------------------------------------------------------
// bf16 MFMA GEMM (m97 pattern): C = A @ Bt^T + bias. 128x128 tile, BK=32,
// global_load_lds staging into no-pad [128][32] LDS. A,B,C all bf16.
// QKV mode: N=1536; q cols scaled by QSCL; v cols routed to Vt[b][h][e][l].
// ---------------------------------------------------------------------------
template<int DO_GELU, int QKV>
__global__ __launch_bounds__(256) void mfma_gemm(
    const short* __restrict__ A, const short* __restrict__ Bt,
    const float* __restrict__ bias, short* __restrict__ C,
    short* __restrict__ VtOut, int M, int N, int K, int lda, int ldc)
{
    __shared__ short As[128][32];
    __shared__ short Bs[128][32];

    const int tid  = threadIdx.x;
    const int wave = tid >> 6;
    const int lane = tid & 63;
    const int qd   = lane >> 4;
    const int sl   = lane & 15;
    const int m0 = blockIdx.y * 128;
    const int n0 = blockIdx.x * 128;
    const int wm = (wave & 1) * 64;
    const int wn = (wave >> 1) * 64;
    const int srow = lane >> 2;          // row within 16-row group
    const int scol = (lane & 3) * 8;     // short offset

    floatx4 acc[4][4];
    const floatx4 fz = {0.f, 0.f, 0.f, 0.f};
    #pragma unroll
    for (int i = 0; i < 4; ++i)
        #pragma unroll
        for (int j = 0; j < 4; ++j) acc[i][j] = fz;

    for (int k0 = 0; k0 < K; k0 += 32) {
        #pragma unroll
        for (int it = 0; it < 2; ++it) {
            const int rg = wave * 2 + it;            // 16-row group 0..7
            const int row = rg * 16 + srow;
            load_lds16(A  + (long)(m0 + row) * lda + k0 + scol, &As[rg * 16][0]);
            load_lds16(Bt + (long)(n0 + row) * K   + k0 + scol, &Bs[rg * 16][0]);
        }
        __syncthreads();

        short8 af[4], bf[4];
        #pragma unroll
        for (int t = 0; t < 4; ++t) {
            af[t] = *(const short8*)&As[wm + t*16 + sl][qd * 8];
            bf[t] = *(const short8*)&Bs[wn + t*16 + sl][qd * 8];
        }
        #pragma unroll
        for (int i = 0; i < 4; ++i)
            #pragma unroll
            for (int j = 0; j < 4; ++j)
                acc[i][j] = __builtin_amdgcn_mfma_f32_16x16x32_bf16(
                    af[i], bf[j], acc[i][j], 0, 0, 0);
        __syncthreads();
    }

    #pragma unroll
    for (int j = 0; j < 4; ++j) {
        const int col = n0 + wn + j*16 + sl;
        const float bv = bias[col];
        #pragma unroll
        for (int i = 0; i < 4; ++i) {
            #pragma unroll
            for (int r = 0; r < 4; ++r) {
                const int row = m0 + wm + i*16 + qd*4 + r;
                float v = acc[i][j][r] + bv;
                if (DO_GELU) v = 0.5f * v * (1.0f + erff(v * 0.70710678118654752f));
                if (QKV) {
                    if (col < 512) v *= QSCL;               // fold softmax scale into Q
                    const short bb = f2b(v);
                    if (col < 1024) {
                        C[(long)row * 1024 + col] = bb;
                    } else {
                        const int e = col - 1024;
                        const int b_ = row >> 11, l = row & 2047;
                        VtOut[(((long)(b_*8 + (e >> 6))) * 64 + (e & 63)) * 2048 + l] = bb;
                    }
                } else {
                    C[(long)row * ldc + col] = f2b(v);
                }
            }
        }
    }
}

// ---------------------------------------------------------------------------
// Flash attention, bf16 MFMA, no-max softmax (scale folded into Q; raw exp2).
// Block = (b, h, 128-query tile), 4 waves x 32 queries. 64 keys/iter.
// QK: [8192][1024] bf16 (q|k). VtG: [b][h][e][2048] bf16. O: [8192][512] bf16.
// P buffer: pitch 72, 8-short granules XOR-swizzled by qd -> conflict-free.
// ---------------------------------------------------------------------------
__global__ __launch_bounds__(256) void mfma_attn(
    const short* __restrict__ QK, const short* __restrict__ VtG,
    short* __restrict__ O)
{
    __shared__ short Qs[128][72];
    __shared__ short Ks[64][72];
    __shared__ short Vs[64][72];       // [e][key]
    __shared__ short Ps[4][32][72];    // per-wave, swizzled

    const int tid  = threadIdx.x;
    const int wave = tid >> 6;
    const int lane = tid & 63;
    const int qd   = lane >> 4;
    const int sl   = lane & 15;

    const int blk = blockIdx.x;
    const int qt = blk & 15;
    const int h  = (blk >> 4) & 7;
    const int b  = blk >> 7;
    const int tok0 = b * LSEQ;
    const int q0 = qt * 128;

    {   // Q stage: 128 rows x 64 shorts
        const int lr = tid >> 1, lc = (tid & 1) * 32;
        const short* qp = QK + (long)(tok0 + q0 + lr) * 1024 + h * EH + lc;
        *(float4*)&Qs[lr][lc]      = *(const float4*)(qp);
        *(float4*)&Qs[lr][lc + 8]  = *(const float4*)(qp + 8);
        *(float4*)&Qs[lr][lc + 16] = *(const float4*)(qp + 16);
        *(float4*)&Qs[lr][lc + 24] = *(const float4*)(qp + 24);
    }
    __syncthreads();

    short8 aq[2][2];
    #pragma unroll
    for (int q2 = 0; q2 < 2; ++q2)
        #pragma unroll
        for (int ks = 0; ks < 2; ++ks)
            aq[q2][ks] = *(const short8*)&Qs[wave*32 + q2*16 + sl][ks*32 + qd*8];

    float l_i[2][4] = {};
    floatx4 oacc[2][4];
    const floatx4 fz = {0.f, 0.f, 0.f, 0.f};
    #pragma unroll
    for (int q2 = 0; q2 < 2; ++q2)
        #pragma unroll
        for (int t = 0; t < 4; ++t) oacc[q2][t] = fz;

    const int klr = tid >> 2, klc = (tid & 3) * 16;
    const long vbase = ((long)(b * NH + h)) * EH * 2048;

    for (int kt = 0; kt < LSEQ / 64; ++kt) {
        const int k0 = kt * 64;
        __syncthreads();   // prior iter done reading Ks/Vs
        {
            const short* kp = QK + (long)(tok0 + k0 + klr) * 1024 + 512 + h * EH + klc;
            *(float4*)&Ks[klr][klc]     = *(const float4*)kp;
            *(float4*)&Ks[klr][klc + 8] = *(const float4*)(kp + 8);
            const short* vp = VtG + vbase + (long)klr * 2048 + k0 + klc;
            *(float4*)&Vs[klr][klc]     = *(const float4*)vp;
            *(float4*)&Vs[klr][klc + 8] = *(const float4*)(vp + 8);
        }
        __syncthreads();

        // S = Q K^T for both query sub-tiles (shared bk frags)
        floatx4 s[2][4];
        #pragma unroll
        for (int q2 = 0; q2 < 2; ++q2)
            #pragma unroll
            for (int t = 0; t < 4; ++t) s[q2][t] = fz;
        #pragma unroll
        for (int ks = 0; ks < 2; ++ks)
            #pragma unroll
            for (int t = 0; t < 4; ++t) {
                short8 bk = *(const short8*)&Ks[t*16 + sl][ks*32 + qd*8];
                s[0][t] = __builtin_amdgcn_mfma_f32_16x16x32_bf16(aq[0][ks], bk, s[0][t], 0, 0, 0);
                s[1][t] = __builtin_amdgcn_mfma_f32_16x16x32_bf16(aq[1][ks], bk, s[1][t], 0, 0, 0);
            }

        // p = exp2(s) (no max); accumulate row partials; store P swizzled
        #pragma unroll
        for (int q2 = 0; q2 < 2; ++q2)
            #pragma unroll
            for (int t = 0; t < 4; ++t) {
                const int pg = (((t*2 + (sl >> 3)) ^ qd) << 3) | (sl & 7);
                #pragma unroll
                for (int r = 0; r < 4; ++r) {
                    const float pv = __builtin_amdgcn_exp2f(s[q2][t][r]);
                    l_i[q2][r] += pv;
                    Ps[wave][q2*16 + qd*4 + r][pg] = (short)(__float_as_uint(pv) >> 16);
                }
            }

        // O += P V (shared bv frags)
        #pragma unroll
        for (int ks = 0; ks < 2; ++ks) {
            const int pgr = ((ks*4 + qd) ^ ((sl >> 2) & 3)) * 8;
            short8 ap0 = *(const short8*)&Ps[wave][sl][pgr];
            short8 ap1 = *(const short8*)&Ps[wave][16 + sl][pgr];
            #pragma unroll
            for (int t = 0; t < 4; ++t) {
                short8 bv = *(const short8*)&Vs[t*16 + sl][ks*32 + qd*8];
                oacc[0][t] = __builtin_amdgcn_mfma_f32_16x16x32_bf16(ap0, bv, oacc[0][t], 0, 0, 0);
                oacc[1][t] = __builtin_amdgcn_mfma_f32_16x16x32_bf16(ap1, bv, oacc[1][t], 0, 0, 0);
            }
        }
    }

    // finalize: reduce row sums across the 16 sl lanes, normalize, store
    float linv[2][4];
    #pragma unroll
    for (int q2 = 0; q2 < 2; ++q2)
        #pragma unroll
        for (int r = 0; r < 4; ++r) {
            float l = l_i[q2][r];
            l += __shfl_xor(l, 1);
            l += __shfl_xor(l, 2);
            l += __shfl_xor(l, 4);
            l += __shfl_xor(l, 8);
            linv[q2][r] = 1.0f / l;
        }
    #pragma unroll
    for (int q2 = 0; q2 < 2; ++q2)
        #pragma unroll
        for (int t = 0; t < 4; ++t)
            #pragma unroll
            for (int r = 0; r < 4; ++r) {
                const int row = tok0 + q0 + wave*32 + q2*16 + qd*4 + r;
                const int col = h * EH + t*16 + sl;
                O[(long)row * DM + col] = f2b(oacc[q2][t][r] * linv[q2][r]);
            }
}

// ---------------------------------------------------------------------------
// out = LN(X + R) * g + beta. X fp32 or bf16, R bf16, out bf16 or fp32.
// ---------------------------------------------------------------------------
template<int X_BF16, int OUT_F32>
__global__ __launch_bounds__(256) void add_ln_kernel(
    const void* __restrict__ Xv, const short* __restrict__ R,
    const float* __restrict__ g, const float* __restrict__ beta,
    void* __restrict__ outv)
{
    const int row = blockIdx.x;
    const int tid = threadIdx.x;
    float x0, x1;
    if (X_BF16) {
        const short* xp = (const short*)Xv + (long)row * DM;
        x0 = b2f(xp[tid]); x1 = b2f(xp[tid + 256]);
    } else {
        const float* xp = (const float*)Xv + (long)row * DM;
        x0 = xp[tid]; x1 = xp[tid + 256];
    }
    const short* rp = R + (long)row * DM;
    const float v0 = x0 + b2f(rp[tid]);
    const float v1 = x1 + b2f(rp[tid + 256]);
    float s = v0 + v1, sq = v0*v0 + v1*v1;
    #pragma unroll
    for (int o = 32; o > 0; o >>= 1) {
        s  += __shfl_down(s, o);
        sq += __shfl_down(sq, o);
    }
    __shared__ float ss[4], ssq[4];
    const int wid = tid >> 6, lane = tid & 63;
    if (lane == 0) { ss[wid] = s; ssq[wid] = sq; }
    __syncthreads();
    const float S  = ss[0] + ss[1] + ss[2] + ss[3];
    const float SQ = ssq[0] + ssq[1] + ssq[2] + ssq[3];
    const float mean = S * (1.0f / DM);
    const float var  = SQ * (1.0f / DM) - mean * mean;
    const float rstd = rsqrtf(var + 1e-5f);
    const float o0 = (v0 - mean) * rstd * g[tid] + beta[tid];
    const float o1 = (v1 - mean) * rstd * g[tid + 256] + beta[tid + 256];
    if (OUT_F32) {
        float* op = (float*)outv + (long)row * DM;
        op[tid] = o0; op[tid + 256] = o1;
    } else {
        short* op = (short*)outv + (long)row * DM;
        op[tid] = f2b(o0); op[tid + 256] = f2b(o1);
    }
}

// ---------------------------------------------------------------------------
extern "C" void kernel_launch(void* const* d_in, const int* in_sizes, int n_in,
                              void* d_out, int out_size, void* d_ws, size_t ws_size,
                              hipStream_t stream)
{
    const float* x   = (const float*)d_in[0];
    const float* Wq  = (const float*)d_in[1];
    const float* bq  = (const float*)d_in[2];
    const float* Wk  = (const float*)d_in[3];
    const float* bk  = (const float*)d_in[4];
    const float* Wv  = (const float*)d_in[5];
    const float* bv  = (const float*)d_in[6];
    const float* Wo  = (const float*)d_in[7];
    const float* bo  = (const float*)d_in[8];
    const float* W1  = (const float*)d_in[9];
    const float* b1  = (const float*)d_in[10];
    const float* W2  = (const float*)d_in[11];
    const float* b2  = (const float*)d_in[12];
    const float* g1  = (const float*)d_in[13];
    const float* be1 = (const float*)d_in[14];
    const float* g2  = (const float*)d_in[15];
    const float* be2 = (const float*)d_in[16];
    float* out = (float*)d_out;

    // workspace: 56.6 MB
    short* ws    = (short*)d_ws;
    short* Wqkvt = ws;                         // [1536][512]
    short* Wot   = Wqkvt + 786432;             // [512][512]
    short* W1t   = Wot + 262144;               // [2048][512]
    short* W2t   = W1t + 1048576;              // [512][2048]
    float* bqkv  = (float*)(W2t + 1048576);    // [1536] fp32
    short* xb    = (short*)(bqkv + 1536);      // [8192][512]  (later x1b)
    short* qk    = xb + 4194304;               // [8192][1024] q|k
    short* VtG   = qk + 8388608;               // [b][h][64][2048]
    short* Ob    = VtG + 4194304;              // [8192][512]
    short* res   = Ob + 4194304;               // [8192][512]  attn_out / ffn_out
    short* hbuf  = qk;                         // [8192][2048] overlays qk|VtG|Ob

    const dim3 blk(256);

    fuse_bias_kernel<<<dim3(6), blk, 0, stream>>>(bq, bk, bv, bqkv);
    transpose_cvt<<<dim3(8, 8),  blk, 0, stream>>>(Wq, Wqkvt,              DM, DM);
    transpose_cvt<<<dim3(8, 8),  blk, 0, stream>>>(Wk, Wqkvt + 512L * DM,  DM, DM);
    transpose_cvt<<<dim3(8, 8),  blk, 0, stream>>>(Wv, Wqkvt + 1024L * DM, DM, DM);
    transpose_cvt<<<dim3(8, 8),  blk, 0, stream>>>(Wo, Wot, DM, DM);
    transpose_cvt<<<dim3(32, 8), blk, 0, stream>>>(W1, W1t, DM, DFF);
    transpose_cvt<<<dim3(8, 32), blk, 0, stream>>>(W2, W2t, DFF, DM);
    cvt_f32_bf16<<<dim3(2048), blk, 0, stream>>>(x, xb);

    // QKV: [8192,512] @ [512,1536] -> qk + VtG (q scaled by QSCL)
    mfma_gemm<0, 1><<<dim3(12, 64), blk, 0, stream>>>(
        xb, Wqkvt, bqkv, qk, VtG, MTOK, QKVW, DM, DM, 0);

    mfma_attn<<<dim3(512), blk, 0, stream>>>(qk, VtG, Ob);

    // Wo: [8192,512] @ [512,512] -> res (bf16)
    mfma_gemm<0, 0><<<dim3(4, 64), blk, 0, stream>>>(
        Ob, Wot, bo, res, nullptr, MTOK, DM, DM, DM, DM);

    // x1b = LN(x + res)  (bf16)
    add_ln_kernel<0, 0><<<dim3(MTOK), blk, 0, stream>>>(x, res, g1, be1, xb);

    // FFN1: [8192,512] @ [512,2048], GELU -> hbuf
    mfma_gemm<1, 0><<<dim3(16, 64), blk, 0, stream>>>(
        xb, W1t, b1, hbuf, nullptr, MTOK, DFF, DM, DM, DFF);

    // FFN2: [8192,2048] @ [2048,512] -> res
    mfma_gemm<0, 0><<<dim3(4, 64), blk, 0, stream>>>(
        hbuf, W2t, b2, res, nullptr, MTOK, DM, DFF, DFF, DM);

    // out = LN(x1b + res)  (fp32)
    add_ln_kernel<1, 1><<<dim3(MTOK), blk, 0, stream>>>(xb, res, g2, be2, out);
}